// Round 6
// baseline (315.345 us; speedup 1.0000x reference)
//
#include <hip/hip_runtime.h>
#include <math.h>

#define NHOP 2
#define MEM 32
#define DIM 64

typedef __attribute__((ext_vector_type(8))) short short8v;
typedef __attribute__((ext_vector_type(4))) float f32x4;

__device__ __forceinline__ float fast_tanh(float x) {
    const float e = __expf(2.f * x);
    return 1.f - 2.f / (e + 1.f);
}

// round-to-nearest-even fp32 -> bf16 bits
__device__ __forceinline__ short bf16b(float x) {
    union { float f; unsigned u; } c; c.f = x;
    const unsigned r = c.u + 0x7fffu + ((c.u >> 16) & 1u);
    return (short)(r >> 16);
}

__global__ __launch_bounds__(256, 3) void ripple_fwd(
    const float* __restrict__ hs,     // (B,2,32,64)
    const float* __restrict__ Rs,     // (B,2,32,64,64)
    const float* __restrict__ ts,     // (B,2,32,64)
    const float* __restrict__ vs,     // (B,64)
    const float* __restrict__ W1_w,   // (64,256)
    const float* __restrict__ W1_b,   // (64)
    const float* __restrict__ W2_w,   // (1,64)
    const float* __restrict__ W2_b,   // (1)
    const float* __restrict__ Wmem_w, // (2,64,192)
    const float* __restrict__ Wmem_b, // (2,64)
    const float* __restrict__ z_w,    // (64,128)
    const float* __restrict__ z_b,    // (64)
    float* __restrict__ out)          // (B)
{
    // B-fragments of W1T (bf16), frag order: frag = kt*4+nt, 64 lanes x 16B each.
    __shared__ uint4 W1B[32 * 64];                 // 32 KB
    __shared__ float Rh_sm[MEM][68];               // stride 68: 16B-aligned rows, low conflict
    __shared__ float M_sm[DIM], o_sm[DIM], onew_sm[DIM], vs_sm[DIM];
    __shared__ float Zp[2][MEM];
    __shared__ float cvec[128];                    // [0..63]=W1_b, [64..127]=W2_w

    const int b   = blockIdx.x;
    const int tid = threadIdx.x;
    const int l   = tid & 63;
    const int wv  = tid >> 6;

    // ---- One-time: stage W1 as bf16 B-frags. Convention (shared with A-gen):
    // frag (kt,nt): lane ll holds f = kt*32 + (ll>>4)*8 + p, n = nt*16 + (ll&15), p=0..7.
    #pragma unroll
    for (int t = 0; t < 8; ++t) {
        const int s    = t * 256 + tid;
        const int frag = s >> 6, ll = s & 63;
        const int kt = frag >> 2, nt = frag & 3;
        const int n  = nt * 16 + (ll & 15);
        const int f0 = kt * 32 + (ll >> 4) * 8;
        const float4 wa = *reinterpret_cast<const float4*>(W1_w + n * 256 + f0);
        const float4 wb = *reinterpret_cast<const float4*>(W1_w + n * 256 + f0 + 4);
        short8v v;
        v[0] = bf16b(wa.x); v[1] = bf16b(wa.y); v[2] = bf16b(wa.z); v[3] = bf16b(wa.w);
        v[4] = bf16b(wb.x); v[5] = bf16b(wb.y); v[6] = bf16b(wb.z); v[7] = bf16b(wb.w);
        *reinterpret_cast<short8v*>(&W1B[s]) = v;
    }
    if (tid < DIM) {
        cvec[tid]      = W1_b[tid];
        cvec[64 + tid] = W2_w[tid];
        const float v = vs[b * DIM + tid];
        M_sm[tid] = v; o_sm[tid] = v; vs_sm[tid] = v;
    }
    // no barrier needed yet: first consumer of W1B/cvec/M/o is P2, after bar1.

    const int s4 = l & 15;    // e-slice: e = 4*s4..4*s4+3
    const int dq = l >> 4;    // row offset within groups of 4

    for (int hop = 0; hop < NHOP; ++hop) {
        const float* __restrict__ Rbase = Rs + (size_t)(b * NHOP + hop) * MEM * DIM * DIM;
        const float* __restrict__ hbase = hs + (size_t)(b * NHOP + hop) * MEM * DIM;
        const float* __restrict__ tbase = ts + (size_t)(b * NHOP + hop) * MEM * DIM;

        // ---- Phase 1: stream R -> Rh_sm. CONTIGUOUS pattern: instruction i of
        // matvec m covers bytes [1024*i, 1024*(i+1)) of the 16KB matrix (exactly
        // the float4-copy microbench pattern). Lane l -> d = 4i + (l>>4),
        // e-slice 4*(l&15). Reduce-scatter leaves lane l owning d = 4*s4+dq.
        #pragma unroll 2
        for (int k = 0; k < 8; ++k) {
            const int m = k * 4 + wv;
            const float* __restrict__ Rm = Rbase + (size_t)m * DIM * DIM;
            const float* __restrict__ hm = hbase + m * DIM;
            const float4 hv = *reinterpret_cast<const float4*>(hm + 4 * s4);
            float a[16];
            #pragma unroll
            for (int i = 0; i < 16; ++i) {
                const float4 r = *reinterpret_cast<const float4*>(Rm + i * 256 + l * 4);
                a[i] = r.x * hv.x + r.y * hv.y + r.z * hv.z + r.w * hv.w;
            }
            // 4-stage reduce-scatter over the 16-lane e-group (static indexing).
            #pragma unroll
            for (int t = 0; t < 4; ++t) {
                const bool up = (s4 >> t) & 1;
                const int half = 8 >> t;
                #pragma unroll
                for (int k2 = 0; k2 < half; ++k2) {
                    const float keepv = up ? a[2 * k2 + 1] : a[2 * k2];
                    const float sendv = up ? a[2 * k2]     : a[2 * k2 + 1];
                    a[k2] = keepv + __shfl_xor(sendv, 1 << t);
                }
            }
            Rh_sm[m][4 * s4 + dq] = a[0];   // 64 distinct d -> 2 lanes/bank, free
        }
        __syncthreads();   // bar1: Rh_sm ready (+ W1B/cvec/M/o on hop 0)

        // ---- Phase 2 (MFMA): preact = z @ W1T ; Z = W2 . tanh(preact + b1)
        // wave wv: mt = wv&1 (m-tile), nh = wv>>1 (n-half: tiles nh*2, nh*2+1)
        {
            const int g   = l >> 4;
            const int col = l & 15;
            const int mt  = wv & 1;
            const int nh  = wv >> 1;
            const int m   = mt * 16 + col;
            f32x4 acc0 = {0.f, 0.f, 0.f, 0.f};
            f32x4 acc1 = {0.f, 0.f, 0.f, 0.f};
            #pragma unroll
            for (int kt = 0; kt < 8; ++kt) {
                const int part = kt >> 1;              // 0:Rh*o 1:Rh*M 2:|Rh-o| 3:|Rh-M|
                const int e0 = (kt & 1) * 32 + g * 8;  // e-range within DIM
                const float4 r0 = *reinterpret_cast<const float4*>(&Rh_sm[m][e0]);
                const float4 r1 = *reinterpret_cast<const float4*>(&Rh_sm[m][e0 + 4]);
                const float* vsrc = (part & 1) ? M_sm : o_sm;
                const float4 q0 = *reinterpret_cast<const float4*>(vsrc + e0);
                const float4 q1 = *reinterpret_cast<const float4*>(vsrc + e0 + 4);
                float zz[8];
                if (part < 2) {
                    zz[0] = r0.x*q0.x; zz[1] = r0.y*q0.y; zz[2] = r0.z*q0.z; zz[3] = r0.w*q0.w;
                    zz[4] = r1.x*q1.x; zz[5] = r1.y*q1.y; zz[6] = r1.z*q1.z; zz[7] = r1.w*q1.w;
                } else {
                    zz[0] = fabsf(r0.x-q0.x); zz[1] = fabsf(r0.y-q0.y);
                    zz[2] = fabsf(r0.z-q0.z); zz[3] = fabsf(r0.w-q0.w);
                    zz[4] = fabsf(r1.x-q1.x); zz[5] = fabsf(r1.y-q1.y);
                    zz[6] = fabsf(r1.z-q1.z); zz[7] = fabsf(r1.w-q1.w);
                }
                short8v a;
                a[0] = bf16b(zz[0]); a[1] = bf16b(zz[1]); a[2] = bf16b(zz[2]); a[3] = bf16b(zz[3]);
                a[4] = bf16b(zz[4]); a[5] = bf16b(zz[5]); a[6] = bf16b(zz[6]); a[7] = bf16b(zz[7]);
                const short8v b0 = *reinterpret_cast<const short8v*>(&W1B[(kt * 4 + nh * 2 + 0) * 64 + l]);
                const short8v b1 = *reinterpret_cast<const short8v*>(&W1B[(kt * 4 + nh * 2 + 1) * 64 + l]);
                acc0 = __builtin_amdgcn_mfma_f32_16x16x32_bf16(a, b0, acc0, 0, 0, 0);
                acc1 = __builtin_amdgcn_mfma_f32_16x16x32_bf16(a, b1, acc1, 0, 0, 0);
            }
            // Epilogue: D[m'][n] at col=l&15, row=4*g+r (m89-verified). Z-partials.
            const int n0 = (nh * 2 + 0) * 16 + col;
            const int n1 = (nh * 2 + 1) * 16 + col;
            const float b1a = cvec[n0], b1b = cvec[n1];
            const float w2a = cvec[64 + n0], w2b = cvec[64 + n1];
            float pz[4];
            #pragma unroll
            for (int r = 0; r < 4; ++r)
                pz[r] = fast_tanh(acc0[r] + b1a) * w2a + fast_tanh(acc1[r] + b1b) * w2b;
            #pragma unroll
            for (int s = 1; s < 16; s <<= 1) {
                pz[0] += __shfl_xor(pz[0], s, 64);
                pz[1] += __shfl_xor(pz[1], s, 64);
                pz[2] += __shfl_xor(pz[2], s, 64);
                pz[3] += __shfl_xor(pz[3], s, 64);
            }
            if (col == 0) {
                #pragma unroll
                for (int r = 0; r < 4; ++r)
                    Zp[nh][mt * 16 + 4 * g + r] = pz[r];
            }
        }
        __syncthreads();   // bar2: Zp ready; Rh_sm free

        // ---- wave0 cluster: softmax + o_new + M update ----
        if (tid < DIM) {
            float mx = -1e30f;
            #pragma unroll
            for (int m = 0; m < MEM; ++m) mx = fmaxf(mx, Zp[0][m] + Zp[1][m]);
            float s = 0.f, accn = 0.f;
            #pragma unroll
            for (int m = 0; m < MEM; ++m) {
                const float e = __expf(Zp[0][m] + Zp[1][m] - mx);
                s += e;
                accn = fmaf(tbase[m * DIM + tid], e, accn);
            }
            const float onew = accn / s;
            onew_sm[tid] = onew;   // wave-internal RAW: lockstep, no barrier

            const float* __restrict__ Wm = Wmem_w + (size_t)(hop * DIM + tid) * 192;
            float acc2 = Wmem_b[hop * DIM + tid];
            #pragma unroll
            for (int k = 0; k < 16; ++k) {
                const float4 w = *reinterpret_cast<const float4*>(Wm + 4 * k);
                acc2 += w.x * M_sm[4*k] + w.y * M_sm[4*k+1] + w.z * M_sm[4*k+2] + w.w * M_sm[4*k+3];
            }
            #pragma unroll
            for (int k = 0; k < 16; ++k) {
                const float4 w = *reinterpret_cast<const float4*>(Wm + 64 + 4 * k);
                acc2 += w.x * onew_sm[4*k] + w.y * onew_sm[4*k+1] + w.z * onew_sm[4*k+2] + w.w * onew_sm[4*k+3];
            }
            #pragma unroll
            for (int k = 0; k < 16; ++k) {
                const float4 w = *reinterpret_cast<const float4*>(Wm + 128 + 4 * k);
                acc2 += w.x * o_sm[4*k] + w.y * o_sm[4*k+1] + w.z * o_sm[4*k+2] + w.w * o_sm[4*k+3];
            }
            M_sm[tid] = fmaxf(acc2, 0.f);
            o_sm[tid] = onew;
        }
        if (hop == 0) __syncthreads();   // bar3: M/o visible to all waves for hop1 P2
    }

    // ---- Final (wave0 only) ----
    if (tid < DIM) {
        const float* __restrict__ zr = z_w + (size_t)tid * 128;
        float u = z_b[tid];
        #pragma unroll
        for (int k = 0; k < 16; ++k) {
            const float4 w = *reinterpret_cast<const float4*>(zr + 4 * k);
            u += w.x * M_sm[4*k] + w.y * M_sm[4*k+1] + w.z * M_sm[4*k+2] + w.w * M_sm[4*k+3];
        }
        #pragma unroll
        for (int k = 0; k < 16; ++k) {
            const float4 w = *reinterpret_cast<const float4*>(zr + 64 + 4 * k);
            u += w.x * vs_sm[4*k] + w.y * vs_sm[4*k+1] + w.z * vs_sm[4*k+2] + w.w * vs_sm[4*k+3];
        }
        float r = vs_sm[tid] * u;
        #pragma unroll
        for (int s = 1; s < 64; s <<= 1) r += __shfl_xor(r, s, 64);
        if (tid == 0) out[b] = r;
    }
}

extern "C" void kernel_launch(void* const* d_in, const int* in_sizes, int n_in,
                              void* d_out, int out_size, void* d_ws, size_t ws_size,
                              hipStream_t stream)
{
    const float* hs     = (const float*)d_in[0];
    const float* Rs     = (const float*)d_in[1];
    const float* ts     = (const float*)d_in[2];
    const float* vs     = (const float*)d_in[3];
    const float* W1_w   = (const float*)d_in[4];
    const float* W1_b   = (const float*)d_in[5];
    const float* W2_w   = (const float*)d_in[6];
    const float* W2_b   = (const float*)d_in[7];
    const float* Wmem_w = (const float*)d_in[8];
    const float* Wmem_b = (const float*)d_in[9];
    const float* z_w    = (const float*)d_in[10];
    const float* z_b    = (const float*)d_in[11];
    float* out = (float*)d_out;

    const int B = out_size;  // 1024
    ripple_fwd<<<B, 256, 0, stream>>>(hs, Rs, ts, vs, W1_w, W1_b, W2_w, W2_b,
                                      Wmem_w, Wmem_b, z_w, z_b, out);
}

// Round 7
// 195.295 us; speedup vs baseline: 1.6147x; 1.6147x over previous
//
#include <hip/hip_runtime.h>
#include <math.h>

#define NHOP 2
#define MEM 32
#define DIM 64

typedef __attribute__((ext_vector_type(8))) short short8v;
typedef __attribute__((ext_vector_type(4))) float f32x4;

__device__ __forceinline__ float fast_tanh(float x) {
    const float e = __expf(2.f * x);
    return 1.f - 2.f / (e + 1.f);
}

// round-to-nearest-even fp32 -> bf16 bits
__device__ __forceinline__ short bf16b(float x) {
    union { float f; unsigned u; } c; c.f = x;
    const unsigned r = c.u + 0x7fffu + ((c.u >> 16) & 1u);
    return (short)(r >> 16);
}

__global__ __launch_bounds__(256, 3) void ripple_fwd(
    const float* __restrict__ hs,     // (B,2,32,64)
    const float* __restrict__ Rs,     // (B,2,32,64,64)
    const float* __restrict__ ts,     // (B,2,32,64)
    const float* __restrict__ vs,     // (B,64)
    const float* __restrict__ W1_w,   // (64,256)
    const float* __restrict__ W1_b,   // (64)
    const float* __restrict__ W2_w,   // (1,64)
    const float* __restrict__ W2_b,   // (1)
    const float* __restrict__ Wmem_w, // (2,64,192)
    const float* __restrict__ Wmem_b, // (2,64)
    const float* __restrict__ z_w,    // (64,128)
    const float* __restrict__ z_b,    // (64)
    float* __restrict__ out)          // (B)
{
    // B-fragments of W1T (bf16), frag order: frag = kt*4+nt, 64 lanes x 16B each.
    __shared__ uint4 W1B[32 * 64];                 // 32 KB
    __shared__ float Rh_sm[MEM][68];               // stride 68: 16B-aligned rows
    __shared__ float part[4][32][17];              // per-wave transpose buf, 8.7 KB
    __shared__ float M_sm[DIM], o_sm[DIM], onew_sm[DIM], vs_sm[DIM];
    __shared__ float Zp[2][MEM];
    __shared__ float cvec[128];                    // [0..63]=W1_b, [64..127]=W2_w

    const int b   = blockIdx.x;
    const int tid = threadIdx.x;
    const int l   = tid & 63;
    const int wv  = tid >> 6;

    // ---- One-time: stage W1 as bf16 B-frags. Convention (shared with A-gen):
    // frag (kt,nt): lane ll holds f = kt*32 + (ll>>4)*8 + p, n = nt*16 + (ll&15), p=0..7.
    #pragma unroll
    for (int t = 0; t < 8; ++t) {
        const int s    = t * 256 + tid;
        const int frag = s >> 6, ll = s & 63;
        const int kt = frag >> 2, nt = frag & 3;
        const int n  = nt * 16 + (ll & 15);
        const int f0 = kt * 32 + (ll >> 4) * 8;
        const float4 wa = *reinterpret_cast<const float4*>(W1_w + n * 256 + f0);
        const float4 wb = *reinterpret_cast<const float4*>(W1_w + n * 256 + f0 + 4);
        short8v v;
        v[0] = bf16b(wa.x); v[1] = bf16b(wa.y); v[2] = bf16b(wa.z); v[3] = bf16b(wa.w);
        v[4] = bf16b(wb.x); v[5] = bf16b(wb.y); v[6] = bf16b(wb.z); v[7] = bf16b(wb.w);
        *reinterpret_cast<short8v*>(&W1B[s]) = v;
    }
    if (tid < DIM) {
        cvec[tid]      = W1_b[tid];
        cvec[64 + tid] = W2_w[tid];
        const float v = vs[b * DIM + tid];
        M_sm[tid] = v; o_sm[tid] = v; vs_sm[tid] = v;
    }
    // no barrier needed yet: first consumer of W1B/cvec/M/o is P2, after bar1.

    const int s4   = l & 15;   // e-slice: e = 4*s4..4*s4+3 (stable per lane)
    const int dq   = l >> 4;   // row-within-4 group
    const int rrow = l & 31;   // reduce row
    const int hi   = l >> 5;   // reduce s-half

    for (int hop = 0; hop < NHOP; ++hop) {
        const float* __restrict__ Rbase = Rs + (size_t)(b * NHOP + hop) * MEM * DIM * DIM;
        const float* __restrict__ hbase = hs + (size_t)(b * NHOP + hop) * MEM * DIM;
        const float* __restrict__ tbase = ts + (size_t)(b * NHOP + hop) * MEM * DIM;

        // ---- Phase 1: stream R -> Rh_sm. Every wave load = 1KB FULLY CONTIGUOUS
        // (addr = base + 16*lane; 16 lines, 4 lanes/line — the float4-copy pattern).
        // Lane l's partial (d = 4i+dq within half, e-slice 4*s4) goes through a
        // per-wave LDS transpose buffer; reduction = 8 scalar reads + 1 shfl.
        #pragma unroll 2
        for (int k = 0; k < 8; ++k) {
            const int m = k * 4 + wv;
            const float* __restrict__ Rm = Rbase + (size_t)m * DIM * DIM;
            const float4 hv = *reinterpret_cast<const float4*>(hbase + m * DIM + 4 * s4);
            #pragma unroll
            for (int half = 0; half < 2; ++half) {
                #pragma unroll
                for (int i = 0; i < 8; ++i) {
                    const float4 r = *reinterpret_cast<const float4*>(
                        Rm + (half * 8 + i) * 256 + 4 * l);   // byte 1024*(8h+i) + 16*l
                    const float p = r.x*hv.x + r.y*hv.y + r.z*hv.z + r.w*hv.w;
                    part[wv][4 * i + dq][s4] = p;
                }
                // reduce: lane pair (rrow, rrow+32) sums s-halves of row rrow
                float a = 0.f;
                #pragma unroll
                for (int j = 0; j < 8; ++j)
                    a += part[wv][rrow][hi * 8 + j];
                a += __shfl_xor(a, 32);
                if (l < 32) Rh_sm[m][half * 32 + rrow] = a;
            }
        }
        __syncthreads();   // bar1: Rh_sm ready (+ W1B/cvec/M/o on hop 0)

        // ---- Phase 2 (MFMA): preact = z @ W1T ; Z = W2 . tanh(preact + b1)
        // wave wv: mt = wv&1 (m-tile), nh = wv>>1 (n-half: tiles nh*2, nh*2+1)
        {
            const int g   = l >> 4;
            const int col = l & 15;
            const int mt  = wv & 1;
            const int nh  = wv >> 1;
            const int m   = mt * 16 + col;
            f32x4 acc0 = {0.f, 0.f, 0.f, 0.f};
            f32x4 acc1 = {0.f, 0.f, 0.f, 0.f};
            #pragma unroll
            for (int kt = 0; kt < 8; ++kt) {
                const int part2 = kt >> 1;             // 0:Rh*o 1:Rh*M 2:|Rh-o| 3:|Rh-M|
                const int e0 = (kt & 1) * 32 + g * 8;  // e-range within DIM
                const float4 r0 = *reinterpret_cast<const float4*>(&Rh_sm[m][e0]);
                const float4 r1 = *reinterpret_cast<const float4*>(&Rh_sm[m][e0 + 4]);
                const float* vsrc = (part2 & 1) ? M_sm : o_sm;
                const float4 q0 = *reinterpret_cast<const float4*>(vsrc + e0);
                const float4 q1 = *reinterpret_cast<const float4*>(vsrc + e0 + 4);
                float zz[8];
                if (part2 < 2) {
                    zz[0] = r0.x*q0.x; zz[1] = r0.y*q0.y; zz[2] = r0.z*q0.z; zz[3] = r0.w*q0.w;
                    zz[4] = r1.x*q1.x; zz[5] = r1.y*q1.y; zz[6] = r1.z*q1.z; zz[7] = r1.w*q1.w;
                } else {
                    zz[0] = fabsf(r0.x-q0.x); zz[1] = fabsf(r0.y-q0.y);
                    zz[2] = fabsf(r0.z-q0.z); zz[3] = fabsf(r0.w-q0.w);
                    zz[4] = fabsf(r1.x-q1.x); zz[5] = fabsf(r1.y-q1.y);
                    zz[6] = fabsf(r1.z-q1.z); zz[7] = fabsf(r1.w-q1.w);
                }
                short8v a;
                a[0] = bf16b(zz[0]); a[1] = bf16b(zz[1]); a[2] = bf16b(zz[2]); a[3] = bf16b(zz[3]);
                a[4] = bf16b(zz[4]); a[5] = bf16b(zz[5]); a[6] = bf16b(zz[6]); a[7] = bf16b(zz[7]);
                const short8v b0 = *reinterpret_cast<const short8v*>(&W1B[(kt * 4 + nh * 2 + 0) * 64 + l]);
                const short8v b1 = *reinterpret_cast<const short8v*>(&W1B[(kt * 4 + nh * 2 + 1) * 64 + l]);
                acc0 = __builtin_amdgcn_mfma_f32_16x16x32_bf16(a, b0, acc0, 0, 0, 0);
                acc1 = __builtin_amdgcn_mfma_f32_16x16x32_bf16(a, b1, acc1, 0, 0, 0);
            }
            // Epilogue: D[m'][n] at col=l&15, row=4*g+r (m89-verified). Z-partials.
            const int n0 = (nh * 2 + 0) * 16 + col;
            const int n1 = (nh * 2 + 1) * 16 + col;
            const float b1a = cvec[n0], b1b = cvec[n1];
            const float w2a = cvec[64 + n0], w2b = cvec[64 + n1];
            float pz[4];
            #pragma unroll
            for (int r = 0; r < 4; ++r)
                pz[r] = fast_tanh(acc0[r] + b1a) * w2a + fast_tanh(acc1[r] + b1b) * w2b;
            #pragma unroll
            for (int s = 1; s < 16; s <<= 1) {
                pz[0] += __shfl_xor(pz[0], s, 64);
                pz[1] += __shfl_xor(pz[1], s, 64);
                pz[2] += __shfl_xor(pz[2], s, 64);
                pz[3] += __shfl_xor(pz[3], s, 64);
            }
            if (col == 0) {
                #pragma unroll
                for (int r = 0; r < 4; ++r)
                    Zp[nh][mt * 16 + 4 * g + r] = pz[r];
            }
        }
        __syncthreads();   // bar2: Zp ready; Rh_sm free

        // ---- wave0 cluster: softmax + o_new + M update ----
        if (tid < DIM) {
            float mx = -1e30f;
            #pragma unroll
            for (int m = 0; m < MEM; ++m) mx = fmaxf(mx, Zp[0][m] + Zp[1][m]);
            float s = 0.f, accn = 0.f;
            #pragma unroll
            for (int m = 0; m < MEM; ++m) {
                const float e = __expf(Zp[0][m] + Zp[1][m] - mx);
                s += e;
                accn = fmaf(tbase[m * DIM + tid], e, accn);
            }
            const float onew = accn / s;
            onew_sm[tid] = onew;   // wave-internal RAW: lockstep, no barrier

            const float* __restrict__ Wm = Wmem_w + (size_t)(hop * DIM + tid) * 192;
            float acc2 = Wmem_b[hop * DIM + tid];
            #pragma unroll
            for (int k = 0; k < 16; ++k) {
                const float4 w = *reinterpret_cast<const float4*>(Wm + 4 * k);
                acc2 += w.x * M_sm[4*k] + w.y * M_sm[4*k+1] + w.z * M_sm[4*k+2] + w.w * M_sm[4*k+3];
            }
            #pragma unroll
            for (int k = 0; k < 16; ++k) {
                const float4 w = *reinterpret_cast<const float4*>(Wm + 64 + 4 * k);
                acc2 += w.x * onew_sm[4*k] + w.y * onew_sm[4*k+1] + w.z * onew_sm[4*k+2] + w.w * onew_sm[4*k+3];
            }
            #pragma unroll
            for (int k = 0; k < 16; ++k) {
                const float4 w = *reinterpret_cast<const float4*>(Wm + 128 + 4 * k);
                acc2 += w.x * o_sm[4*k] + w.y * o_sm[4*k+1] + w.z * o_sm[4*k+2] + w.w * o_sm[4*k+3];
            }
            M_sm[tid] = fmaxf(acc2, 0.f);
            o_sm[tid] = onew;
        }
        if (hop == 0) __syncthreads();   // bar3: M/o visible to all waves for hop1 P2
    }

    // ---- Final (wave0 only) ----
    if (tid < DIM) {
        const float* __restrict__ zr = z_w + (size_t)tid * 128;
        float u = z_b[tid];
        #pragma unroll
        for (int k = 0; k < 16; ++k) {
            const float4 w = *reinterpret_cast<const float4*>(zr + 4 * k);
            u += w.x * M_sm[4*k] + w.y * M_sm[4*k+1] + w.z * M_sm[4*k+2] + w.w * M_sm[4*k+3];
        }
        #pragma unroll
        for (int k = 0; k < 16; ++k) {
            const float4 w = *reinterpret_cast<const float4*>(zr + 64 + 4 * k);
            u += w.x * vs_sm[4*k] + w.y * vs_sm[4*k+1] + w.z * vs_sm[4*k+2] + w.w * vs_sm[4*k+3];
        }
        float r = vs_sm[tid] * u;
        #pragma unroll
        for (int s = 1; s < 64; s <<= 1) r += __shfl_xor(r, s, 64);
        if (tid == 0) out[b] = r;
    }
}

extern "C" void kernel_launch(void* const* d_in, const int* in_sizes, int n_in,
                              void* d_out, int out_size, void* d_ws, size_t ws_size,
                              hipStream_t stream)
{
    const float* hs     = (const float*)d_in[0];
    const float* Rs     = (const float*)d_in[1];
    const float* ts     = (const float*)d_in[2];
    const float* vs     = (const float*)d_in[3];
    const float* W1_w   = (const float*)d_in[4];
    const float* W1_b   = (const float*)d_in[5];
    const float* W2_w   = (const float*)d_in[6];
    const float* W2_b   = (const float*)d_in[7];
    const float* Wmem_w = (const float*)d_in[8];
    const float* Wmem_b = (const float*)d_in[9];
    const float* z_w    = (const float*)d_in[10];
    const float* z_b    = (const float*)d_in[11];
    float* out = (float*)d_out;

    const int B = out_size;  // 1024
    ripple_fwd<<<B, 256, 0, stream>>>(hs, Rs, ts, vs, W1_w, W1_b, W2_w, W2_b,
                                      Wmem_w, Wmem_b, z_w, z_b, out);
}

// Round 9
// 176.936 us; speedup vs baseline: 1.7823x; 1.1038x over previous
//
#include <hip/hip_runtime.h>
#include <math.h>

#define NHOP 2
#define MEM 32
#define DIM 64

typedef __attribute__((ext_vector_type(8))) short short8v;
typedef __attribute__((ext_vector_type(4))) float f32x4;

__device__ __forceinline__ float fast_tanh(float x) {
    const float e = __expf(2.f * x);
    return 1.f - 2.f / (e + 1.f);
}

// round-to-nearest-even fp32 -> bf16 bits
__device__ __forceinline__ short bf16b(float x) {
    union { float f; unsigned u; } c; c.f = x;
    const unsigned r = c.u + 0x7fffu + ((c.u >> 16) & 1u);
    return (short)(r >> 16);
}

__global__ __launch_bounds__(256, 3) void ripple_fwd(
    const float* __restrict__ hs,     // (B,2,32,64)
    const float* __restrict__ Rs,     // (B,2,32,64,64)
    const float* __restrict__ ts,     // (B,2,32,64)
    const float* __restrict__ vs,     // (B,64)
    const float* __restrict__ W1_w,   // (64,256)
    const float* __restrict__ W1_b,   // (64)
    const float* __restrict__ W2_w,   // (1,64)
    const float* __restrict__ W2_b,   // (1)
    const float* __restrict__ Wmem_w, // (2,64,192)
    const float* __restrict__ Wmem_b, // (2,64)
    const float* __restrict__ z_w,    // (64,128)
    const float* __restrict__ z_b,    // (64)
    float* __restrict__ out)          // (B)
{
    // B-fragments of W1T (bf16), frag order: frag = kt*4+nt, 64 lanes x 16B each.
    __shared__ uint4 W1B[32 * 64];                        // 32 KB
    __shared__ float Rh_sm[MEM][68];                      // stride 68: 16B-aligned rows
    __shared__ __align__(16) float part[4][32][20];       // per-wave transpose buf, 10.2 KB
    __shared__ float M_sm[DIM], o_sm[DIM], onew_sm[DIM], vs_sm[DIM];
    __shared__ float Zp[2][MEM];
    __shared__ float cvec[128];                           // [0..63]=W1_b, [64..127]=W2_w

    const int b   = blockIdx.x;
    const int tid = threadIdx.x;
    const int l   = tid & 63;
    const int wv  = tid >> 6;

    // ---- One-time: stage W1 as bf16 B-frags. Convention (shared with A-gen):
    // frag (kt,nt): lane ll holds f = kt*32 + (ll>>4)*8 + p, n = nt*16 + (ll&15), p=0..7.
    #pragma unroll
    for (int t = 0; t < 8; ++t) {
        const int s    = t * 256 + tid;
        const int frag = s >> 6, ll = s & 63;
        const int kt = frag >> 2, nt = frag & 3;
        const int n  = nt * 16 + (ll & 15);
        const int f0 = kt * 32 + (ll >> 4) * 8;
        const float4 wa = *reinterpret_cast<const float4*>(W1_w + n * 256 + f0);
        const float4 wb = *reinterpret_cast<const float4*>(W1_w + n * 256 + f0 + 4);
        short8v v;
        v[0] = bf16b(wa.x); v[1] = bf16b(wa.y); v[2] = bf16b(wa.z); v[3] = bf16b(wa.w);
        v[4] = bf16b(wb.x); v[5] = bf16b(wb.y); v[6] = bf16b(wb.z); v[7] = bf16b(wb.w);
        *reinterpret_cast<short8v*>(&W1B[s]) = v;
    }
    if (tid < DIM) {
        cvec[tid]      = W1_b[tid];
        cvec[64 + tid] = W2_w[tid];
        const float v = vs[b * DIM + tid];
        M_sm[tid] = v; o_sm[tid] = v; vs_sm[tid] = v;
    }
    // no barrier needed yet: first consumer of W1B/cvec/M/o is P2, after bar1.

    const int s4   = l & 15;   // e-slice: e = 4*s4..4*s4+3 (stable per lane)
    const int dq   = l >> 4;   // row-within-4 group
    const int rrow = l & 31;   // reduce row
    const int hi   = l >> 5;   // reduce s-half

    const float* __restrict__ Rbase0 = Rs + (size_t)(b * NHOP + 0) * MEM * DIM * DIM;
    const float* __restrict__ Rbase1 = Rs + (size_t)(b * NHOP + 1) * MEM * DIM * DIM;
    const float* __restrict__ hbase0 = hs + (size_t)(b * NHOP + 0) * MEM * DIM;
    const float* __restrict__ hbase1 = hs + (size_t)(b * NHOP + 1) * MEM * DIM;
    const float* __restrict__ tbase0 = ts + (size_t)(b * NHOP + 0) * MEM * DIM;
    const float* __restrict__ tbase1 = ts + (size_t)(b * NHOP + 1) * MEM * DIM;

    // ---- P1: one matvec, contiguous 1KB wave loads + LDS-transpose reduce ----
    auto p1 = [&](const float* __restrict__ Rbase, const float* __restrict__ hbase,
                  const int m) {
        const float* __restrict__ Rm = Rbase + (size_t)m * DIM * DIM;
        const float4 hv = *reinterpret_cast<const float4*>(hbase + m * DIM + 4 * s4);
        #pragma unroll
        for (int half = 0; half < 2; ++half) {
            #pragma unroll
            for (int i = 0; i < 8; ++i) {
                const f32x4* rp = reinterpret_cast<const f32x4*>(
                    Rm + (half * 8 + i) * 256 + 4 * l);   // byte 1024*(8h+i) + 16*l
                const f32x4 r = __builtin_nontemporal_load(rp);   // zero-reuse stream
                part[wv][4 * i + dq][s4] = r.x*hv.x + r.y*hv.y + r.z*hv.z + r.w*hv.w;
            }
            const float4 pa = *reinterpret_cast<const float4*>(&part[wv][rrow][hi * 8]);
            const float4 pb = *reinterpret_cast<const float4*>(&part[wv][rrow][hi * 8 + 4]);
            float a = ((pa.x + pa.y) + (pa.z + pa.w)) + ((pb.x + pb.y) + (pb.z + pb.w));
            a += __shfl_xor(a, 32);
            if (l < 32) Rh_sm[m][half * 32 + rrow] = a;
        }
    };

    // ---- P2: MFMA z@W1T -> Z partials (wave wv: mt=wv&1, nh=wv>>1) ----
    auto p2 = [&]() {
        const int g   = l >> 4;
        const int col = l & 15;
        const int mt  = wv & 1;
        const int nh  = wv >> 1;
        const int m   = mt * 16 + col;
        f32x4 acc0 = {0.f, 0.f, 0.f, 0.f};
        f32x4 acc1 = {0.f, 0.f, 0.f, 0.f};
        #pragma unroll
        for (int kt = 0; kt < 8; ++kt) {
            const int pt = kt >> 1;                // 0:Rh*o 1:Rh*M 2:|Rh-o| 3:|Rh-M|
            const int e0 = (kt & 1) * 32 + g * 8;  // e-range within DIM
            const float4 r0 = *reinterpret_cast<const float4*>(&Rh_sm[m][e0]);
            const float4 r1 = *reinterpret_cast<const float4*>(&Rh_sm[m][e0 + 4]);
            const float* vsrc = (pt & 1) ? M_sm : o_sm;
            const float4 q0 = *reinterpret_cast<const float4*>(vsrc + e0);
            const float4 q1 = *reinterpret_cast<const float4*>(vsrc + e0 + 4);
            float zz[8];
            if (pt < 2) {
                zz[0] = r0.x*q0.x; zz[1] = r0.y*q0.y; zz[2] = r0.z*q0.z; zz[3] = r0.w*q0.w;
                zz[4] = r1.x*q1.x; zz[5] = r1.y*q1.y; zz[6] = r1.z*q1.z; zz[7] = r1.w*q1.w;
            } else {
                zz[0] = fabsf(r0.x-q0.x); zz[1] = fabsf(r0.y-q0.y);
                zz[2] = fabsf(r0.z-q0.z); zz[3] = fabsf(r0.w-q0.w);
                zz[4] = fabsf(r1.x-q1.x); zz[5] = fabsf(r1.y-q1.y);
                zz[6] = fabsf(r1.z-q1.z); zz[7] = fabsf(r1.w-q1.w);
            }
            short8v a;
            a[0] = bf16b(zz[0]); a[1] = bf16b(zz[1]); a[2] = bf16b(zz[2]); a[3] = bf16b(zz[3]);
            a[4] = bf16b(zz[4]); a[5] = bf16b(zz[5]); a[6] = bf16b(zz[6]); a[7] = bf16b(zz[7]);
            const short8v b0 = *reinterpret_cast<const short8v*>(&W1B[(kt * 4 + nh * 2 + 0) * 64 + l]);
            const short8v b1 = *reinterpret_cast<const short8v*>(&W1B[(kt * 4 + nh * 2 + 1) * 64 + l]);
            acc0 = __builtin_amdgcn_mfma_f32_16x16x32_bf16(a, b0, acc0, 0, 0, 0);
            acc1 = __builtin_amdgcn_mfma_f32_16x16x32_bf16(a, b1, acc1, 0, 0, 0);
        }
        // Epilogue: D[m'][n] at col=l&15, row=4*g+r (m89-verified). Z-partials.
        const int n0 = (nh * 2 + 0) * 16 + col;
        const int n1 = (nh * 2 + 1) * 16 + col;
        const float b1a = cvec[n0], b1b = cvec[n1];
        const float w2a = cvec[64 + n0], w2b = cvec[64 + n1];
        float pz[4];
        #pragma unroll
        for (int r = 0; r < 4; ++r)
            pz[r] = fast_tanh(acc0[r] + b1a) * w2a + fast_tanh(acc1[r] + b1b) * w2b;
        #pragma unroll
        for (int s = 1; s < 16; s <<= 1) {
            pz[0] += __shfl_xor(pz[0], s, 64);
            pz[1] += __shfl_xor(pz[1], s, 64);
            pz[2] += __shfl_xor(pz[2], s, 64);
            pz[3] += __shfl_xor(pz[3], s, 64);
        }
        if (col == 0) {
            #pragma unroll
            for (int r = 0; r < 4; ++r)
                Zp[nh][mt * 16 + 4 * g + r] = pz[r];
        }
    };

    // ---- cluster: softmax + o_new + M update (wave0's 64 lanes only) ----
    auto cluster = [&](const int hop, const float* __restrict__ tbase) {
        if (tid < DIM) {
            float mx = -1e30f;
            #pragma unroll
            for (int m = 0; m < MEM; ++m) mx = fmaxf(mx, Zp[0][m] + Zp[1][m]);
            float s = 0.f, accn = 0.f;
            #pragma unroll
            for (int m = 0; m < MEM; ++m) {
                const float e = __expf(Zp[0][m] + Zp[1][m] - mx);
                s += e;
                accn = fmaf(tbase[m * DIM + tid], e, accn);
            }
            const float onew = accn / s;
            onew_sm[tid] = onew;   // wave-internal RAW: lockstep, no barrier

            const float* __restrict__ Wm = Wmem_w + (size_t)(hop * DIM + tid) * 192;
            float acc2 = Wmem_b[hop * DIM + tid];
            #pragma unroll
            for (int k = 0; k < 16; ++k) {
                const float4 w = *reinterpret_cast<const float4*>(Wm + 4 * k);
                acc2 += w.x * M_sm[4*k] + w.y * M_sm[4*k+1] + w.z * M_sm[4*k+2] + w.w * M_sm[4*k+3];
            }
            #pragma unroll
            for (int k = 0; k < 16; ++k) {
                const float4 w = *reinterpret_cast<const float4*>(Wm + 64 + 4 * k);
                acc2 += w.x * onew_sm[4*k] + w.y * onew_sm[4*k+1] + w.z * onew_sm[4*k+2] + w.w * onew_sm[4*k+3];
            }
            #pragma unroll
            for (int k = 0; k < 16; ++k) {
                const float4 w = *reinterpret_cast<const float4*>(Wm + 128 + 4 * k);
                acc2 += w.x * o_sm[4*k] + w.y * o_sm[4*k+1] + w.z * o_sm[4*k+2] + w.w * o_sm[4*k+3];
            }
            M_sm[tid] = fmaxf(acc2, 0.f);
            o_sm[tid] = onew;
        }
    };

    // ================= schedule =================
    // P1 hop0 (all waves, m = k*4+wv)
    #pragma unroll 2
    for (int k = 0; k < 8; ++k)
        p1(Rbase0, hbase0, k * 4 + wv);
    __syncthreads();            // bar1: Rh_sm(hop0) + W1B/cvec/M/o ready

    p2();                       // P2 hop0
    __syncthreads();            // bar2: Zp ready; Rh_sm free

    // Overlap: waves1-3 stream hop1 (m 0..23) while wave0 runs cluster(hop0),
    // then wave0 streams m 24..31.
    if (wv == 0) {
        cluster(0, tbase0);
        #pragma unroll 2
        for (int j = 0; j < 8; ++j)
            p1(Rbase1, hbase1, 24 + j);
    } else {
        #pragma unroll 2
        for (int j = 0; j < 8; ++j)
            p1(Rbase1, hbase1, (wv - 1) * 8 + j);
    }
    __syncthreads();            // bar3: Rh_sm(hop1) + M/o ready

    p2();                       // P2 hop1
    __syncthreads();            // bar4: Zp ready

    if (wv == 0) {
        cluster(1, tbase1);
        // ---- Final (wave0 only; M/o written by this wave) ----
        if (tid < DIM) {
            const float* __restrict__ zr = z_w + (size_t)tid * 128;
            float u = z_b[tid];
            #pragma unroll
            for (int k = 0; k < 16; ++k) {
                const float4 w = *reinterpret_cast<const float4*>(zr + 4 * k);
                u += w.x * M_sm[4*k] + w.y * M_sm[4*k+1] + w.z * M_sm[4*k+2] + w.w * M_sm[4*k+3];
            }
            #pragma unroll
            for (int k = 0; k < 16; ++k) {
                const float4 w = *reinterpret_cast<const float4*>(zr + 64 + 4 * k);
                u += w.x * vs_sm[4*k] + w.y * vs_sm[4*k+1] + w.z * vs_sm[4*k+2] + w.w * vs_sm[4*k+3];
            }
            float r = vs_sm[tid] * u;
            #pragma unroll
            for (int s = 1; s < 64; s <<= 1) r += __shfl_xor(r, s, 64);
            if (tid == 0) out[b] = r;
        }
    }
}

extern "C" void kernel_launch(void* const* d_in, const int* in_sizes, int n_in,
                              void* d_out, int out_size, void* d_ws, size_t ws_size,
                              hipStream_t stream)
{
    const float* hs     = (const float*)d_in[0];
    const float* Rs     = (const float*)d_in[1];
    const float* ts     = (const float*)d_in[2];
    const float* vs     = (const float*)d_in[3];
    const float* W1_w   = (const float*)d_in[4];
    const float* W1_b   = (const float*)d_in[5];
    const float* W2_w   = (const float*)d_in[6];
    const float* W2_b   = (const float*)d_in[7];
    const float* Wmem_w = (const float*)d_in[8];
    const float* Wmem_b = (const float*)d_in[9];
    const float* z_w    = (const float*)d_in[10];
    const float* z_b    = (const float*)d_in[11];
    float* out = (float*)d_out;

    const int B = out_size;  // 1024
    ripple_fwd<<<B, 256, 0, stream>>>(hs, Rs, ts, vs, W1_w, W1_b, W2_w, W2_b,
                                      Wmem_w, Wmem_b, z_w, z_b, out);
}